// Round 1
// baseline (520.893 us; speedup 1.0000x reference)
//
#include <hip/hip_runtime.h>
#include <stdint.h>

#define B_ROWS 8192
#define P_ROWS 4096
#define D_DIM  1024
#define K_TOP  6

typedef __attribute__((ext_vector_type(8))) short short8;
typedef __attribute__((ext_vector_type(4))) float floatx4;

static __device__ __forceinline__ float bf2f(unsigned short h) {
  return __uint_as_float(((unsigned)h) << 16);
}
static __device__ __forceinline__ unsigned short f2bf(float f) {
  unsigned u = __float_as_uint(f);
  u += 0x7FFFu + ((u >> 16) & 1u);   // RNE
  return (unsigned short)(u >> 16);
}

// ---------------- fp32 -> bf16 convert (x4 vectorized) ----------------
__global__ void convert_bf16_kernel(const float* __restrict__ src,
                                    unsigned short* __restrict__ dst, int n) {
  int i = (blockIdx.x * blockDim.x + threadIdx.x) * 4;
  if (i >= n) return;
  float4 v = *(const float4*)(src + i);
  ushort4 o;
  o.x = f2bf(v.x); o.y = f2bf(v.y); o.z = f2bf(v.z); o.w = f2bf(v.w);
  *(ushort4*)(dst + i) = o;
}

// ---------------- top-6 of 4096 logits per row, one wave per row ----------------
__global__ __launch_bounds__(256) void topk6_kernel(const float* __restrict__ logits,
                                                    int* __restrict__ out) {
  const int wid = threadIdx.x >> 6;
  const int lane = threadIdx.x & 63;
  const int row = blockIdx.x * 4 + wid;
  const float* lp = logits + (size_t)row * P_ROWS;

  unsigned long long keys[64];
#pragma unroll
  for (int i = 0; i < 64; ++i) {
    unsigned u = __float_as_uint(lp[i * 64 + lane]);
    unsigned m = ((unsigned)((int)u >> 31)) | 0x80000000u;  // monotone order map
    u ^= m;
    keys[i] = (((unsigned long long)u) << 32) |
              (unsigned long long)(0xFFFFFFFFu - (unsigned)(i * 64 + lane));
  }
#pragma unroll
  for (int it = 0; it < K_TOP; ++it) {
    unsigned long long best = 0;
#pragma unroll
    for (int i = 0; i < 64; ++i) best = keys[i] > best ? keys[i] : best;
#pragma unroll
    for (int off = 32; off > 0; off >>= 1) {
      unsigned long long o = __shfl_xor(best, off);
      best = o > best ? o : best;
    }
    int widx = (int)(0xFFFFFFFFu - (unsigned)(best & 0xFFFFFFFFull));
    if (lane == 0) out[row * K_TOP + it] = widx;
    const int slot = widx >> 6, owner = widx & 63;
#pragma unroll
    for (int i = 0; i < 64; ++i)
      if (i == slot && lane == owner) keys[i] = 0;  // static-index mask (no scratch)
  }
}

// ---------------- bf16 MFMA GEMM, C[m,n] = sum_d A[m,d]*W[n,d] + bias[n] ----------------
// 128x128 tile, BK=64, 4 waves (2x2 of 64x64), 4x4 MFMA 16x16x32 per wave.
typedef __attribute__((address_space(3))) unsigned int lds32_t;
typedef const __attribute__((address_space(1))) unsigned int g32_t;

static __device__ __forceinline__ void gld_lds16(const unsigned short* g, unsigned short* l) {
  __builtin_amdgcn_global_load_lds((g32_t*)(uintptr_t)g,
                                   (lds32_t*)(unsigned int)(uintptr_t)l, 16, 0, 0);
}

template <bool OUT_BF16>
__global__ __launch_bounds__(256) void gemm_bt_kernel(
    const unsigned short* __restrict__ A,   // [M,1024] bf16 row-major
    const unsigned short* __restrict__ Bw,  // [1024,1024] bf16 row-major (torch Linear W)
    const float* __restrict__ bias,         // [1024]
    void* __restrict__ Cout) {
  constexpr int Kd = 1024, Nd = 1024, BK = 64;
  __shared__ unsigned short sA[128 * BK];
  __shared__ unsigned short sB[128 * BK];

  const int tid = threadIdx.x;
  const int wid = tid >> 6, lane = tid & 63;
  const int m0 = blockIdx.y * 128, n0 = blockIdx.x * 128;
  const int wm = (wid & 1) * 64, wn = (wid >> 1) * 64;

  floatx4 acc[4][4];
#pragma unroll
  for (int mt = 0; mt < 4; ++mt)
#pragma unroll
    for (int nt = 0; nt < 4; ++nt) acc[mt][nt] = (floatx4){0.f, 0.f, 0.f, 0.f};

  const int ld_row = lane >> 3;         // 0..7 within 8-row chunk
  const int ld_col = (lane & 7) * 8;    // element col within BK

  for (int kt = 0; kt < Kd / BK; ++kt) {
    const int k0 = kt * BK;
    __syncthreads();
#pragma unroll
    for (int c = 0; c < 4; ++c) {
      const int ch = wid * 4 + c;           // 16 chunks of 8 rows
      const int r = ch * 8 + ld_row;
      gld_lds16(A  + (size_t)(m0 + r) * Kd + k0 + ld_col, sA + ch * 512);
      gld_lds16(Bw + (size_t)(n0 + r) * Kd + k0 + ld_col, sB + ch * 512);
    }
    __syncthreads();
#pragma unroll
    for (int ks = 0; ks < 2; ++ks) {
      const int kk = ks * 32 + (lane >> 4) * 8;
      short8 a[4], b[4];
#pragma unroll
      for (int t = 0; t < 4; ++t) {
        a[t] = *(const short8*)(sA + (wm + t * 16 + (lane & 15)) * BK + kk);
        b[t] = *(const short8*)(sB + (wn + t * 16 + (lane & 15)) * BK + kk);
      }
#pragma unroll
      for (int mt = 0; mt < 4; ++mt)
#pragma unroll
        for (int nt = 0; nt < 4; ++nt)
          acc[mt][nt] = __builtin_amdgcn_mfma_f32_16x16x32_bf16(a[mt], b[nt], acc[mt][nt], 0, 0, 0);
    }
  }

  const int er = lane >> 4;   // C/D: row=(lane>>4)*4+reg, col=lane&15 (m89-verified)
  const int ec = lane & 15;
#pragma unroll
  for (int mt = 0; mt < 4; ++mt) {
#pragma unroll
    for (int nt = 0; nt < 4; ++nt) {
      const int col = n0 + wn + nt * 16 + ec;
      const float bv = bias[col];
#pragma unroll
      for (int r = 0; r < 4; ++r) {
        const int row = m0 + wm + mt * 16 + er * 4 + r;
        const float v = acc[mt][nt][r] + bv;
        if (OUT_BF16)
          ((unsigned short*)Cout)[(size_t)row * Nd + col] = f2bf(v);
        else
          ((float*)Cout)[(size_t)row * Nd + col] = v;
      }
    }
  }
}

// ---------------- attention: one block per row, one wave = one head-dim (64) ----------------
__global__ __launch_bounds__(256) void attn_kernel(
    const unsigned short* __restrict__ q2,  // [B,1024] bf16
    const unsigned short* __restrict__ kb,  // [P,1024] bf16
    const unsigned short* __restrict__ vb,  // [P,1024] bf16
    const int* __restrict__ topk,           // [B,6]
    unsigned short* __restrict__ ctx,       // [B,1024] bf16 out
    float* __restrict__ attnw) {            // [B,6] fp32 out
  const int b = blockIdx.x;
  const int wid = threadIdx.x >> 6, lane = threadIdx.x & 63;
  __shared__ float wsum[4][K_TOP];

  int idx[K_TOP];
#pragma unroll
  for (int j = 0; j < K_TOP; ++j) idx[j] = topk[b * K_TOP + j];

  float hw[K_TOP] = {0.f, 0.f, 0.f, 0.f, 0.f, 0.f};
#pragma unroll
  for (int hh = 0; hh < 4; ++hh) {
    const int h = wid * 4 + hh;
    const int off = h * 64 + lane;
    const float qv = bf2f(q2[(size_t)b * D_DIM + off]);
    float s[K_TOP];
#pragma unroll
    for (int j = 0; j < K_TOP; ++j)
      s[j] = qv * bf2f(kb[(size_t)idx[j] * D_DIM + off]);
#pragma unroll
    for (int j = 0; j < K_TOP; ++j)
#pragma unroll
      for (int o = 32; o > 0; o >>= 1) s[j] += __shfl_xor(s[j], o);

    float mx = -1e30f;
#pragma unroll
    for (int j = 0; j < K_TOP; ++j) mx = fmaxf(mx, s[j] * 0.125f);
    float e[K_TOP], sum = 0.f;
#pragma unroll
    for (int j = 0; j < K_TOP; ++j) { e[j] = __expf(s[j] * 0.125f - mx); sum += e[j]; }
    const float inv = 1.0f / sum;

    float o = 0.f;
#pragma unroll
    for (int j = 0; j < K_TOP; ++j) {
      const float w = e[j] * inv;
      hw[j] += w;
      o += w * bf2f(vb[(size_t)idx[j] * D_DIM + off]);
    }
    ctx[(size_t)b * D_DIM + off] = f2bf(o);
  }
  if (lane == 0) {
#pragma unroll
    for (int j = 0; j < K_TOP; ++j) wsum[wid][j] = hw[j];
  }
  __syncthreads();
  if (threadIdx.x < K_TOP) {
    const float t = wsum[0][threadIdx.x] + wsum[1][threadIdx.x] +
                    wsum[2][threadIdx.x] + wsum[3][threadIdx.x];
    attnw[(size_t)b * K_TOP + threadIdx.x] = t * (1.0f / 16.0f);
  }
}

extern "C" void kernel_launch(void* const* d_in, const int* in_sizes, int n_in,
                              void* d_out, int out_size, void* d_ws, size_t ws_size,
                              hipStream_t stream) {
  const float* query   = (const float*)d_in[0];
  const float* bank    = (const float*)d_in[1];
  const float* logits  = (const float*)d_in[2];
  const float* Wq_proj = (const float*)d_in[3];
  const float* bq_proj = (const float*)d_in[4];
  const float* Wp_proj = (const float*)d_in[5];
  const float* bp_proj = (const float*)d_in[6];
  const float* Wq      = (const float*)d_in[7];
  const float* bq      = (const float*)d_in[8];
  const float* Wk      = (const float*)d_in[9];
  const float* bk      = (const float*)d_in[10];
  const float* Wv      = (const float*)d_in[11];
  const float* bv      = (const float*)d_in[12];
  const float* Wo      = (const float*)d_in[13];
  const float* bo      = (const float*)d_in[14];

  char* ws = (char*)d_ws;
  size_t off = 0;
  auto alloc = [&](size_t bytes) {
    void* p = ws + off;
    off += (bytes + 255) & ~(size_t)255;
    return p;
  };
  unsigned short* q_bf    = (unsigned short*)alloc((size_t)B_ROWS * D_DIM * 2); // query, then q2
  unsigned short* bank_bf = (unsigned short*)alloc((size_t)P_ROWS * D_DIM * 2); // bank, then kb
  unsigned short* q1_bf   = (unsigned short*)alloc((size_t)B_ROWS * D_DIM * 2); // q1, then ctx
  unsigned short* pb_bf   = (unsigned short*)alloc((size_t)P_ROWS * D_DIM * 2);
  unsigned short* vb_bf   = (unsigned short*)alloc((size_t)P_ROWS * D_DIM * 2);
  unsigned short* wqp_bf  = (unsigned short*)alloc((size_t)D_DIM * D_DIM * 2);
  unsigned short* wpp_bf  = (unsigned short*)alloc((size_t)D_DIM * D_DIM * 2);
  unsigned short* wq_bf   = (unsigned short*)alloc((size_t)D_DIM * D_DIM * 2);
  unsigned short* wk_bf   = (unsigned short*)alloc((size_t)D_DIM * D_DIM * 2);
  unsigned short* wv_bf   = (unsigned short*)alloc((size_t)D_DIM * D_DIM * 2);
  unsigned short* wo_bf   = (unsigned short*)alloc((size_t)D_DIM * D_DIM * 2);
  int* topk               = (int*)alloc((size_t)B_ROWS * K_TOP * 4);

  float* out_ctx  = (float*)d_out;
  float* out_attn = out_ctx + (size_t)B_ROWS * D_DIM;

  auto conv = [&](const float* s, unsigned short* d, int n) {
    convert_bf16_kernel<<<n / 1024, 256, 0, stream>>>(s, d, n);
  };
  conv(query, q_bf, B_ROWS * D_DIM);
  conv(bank, bank_bf, P_ROWS * D_DIM);
  conv(Wq_proj, wqp_bf, D_DIM * D_DIM);
  conv(Wp_proj, wpp_bf, D_DIM * D_DIM);
  conv(Wq, wq_bf, D_DIM * D_DIM);
  conv(Wk, wk_bf, D_DIM * D_DIM);
  conv(Wv, wv_bf, D_DIM * D_DIM);
  conv(Wo, wo_bf, D_DIM * D_DIM);

  topk6_kernel<<<B_ROWS / 4, 256, 0, stream>>>(logits, topk);

  auto gemm_bf = [&](const unsigned short* A, const unsigned short* W, const float* bias,
                     unsigned short* C, int M) {
    dim3 grid(D_DIM / 128, M / 128);
    gemm_bt_kernel<true><<<grid, 256, 0, stream>>>(A, W, bias, (void*)C);
  };
  gemm_bf(q_bf,    wqp_bf, bq_proj, q1_bf,   B_ROWS);  // q1
  gemm_bf(bank_bf, wpp_bf, bp_proj, pb_bf,   P_ROWS);  // projected bank
  gemm_bf(q1_bf,   wq_bf,  bq,      q_bf,    B_ROWS);  // q2 (reuse q_bf)
  gemm_bf(pb_bf,   wk_bf,  bk,      bank_bf, P_ROWS);  // k_bank (reuse bank_bf)
  gemm_bf(pb_bf,   wv_bf,  bv,      vb_bf,   P_ROWS);  // v_bank

  attn_kernel<<<B_ROWS, 256, 0, stream>>>(q_bf, bank_bf, vb_bf, topk, q1_bf, out_attn);

  dim3 grid2(D_DIM / 128, B_ROWS / 128);
  gemm_bt_kernel<false><<<grid2, 256, 0, stream>>>(q1_bf, wo_bf, bo, d_out);  // context
}

// Round 2
// 478.194 us; speedup vs baseline: 1.0893x; 1.0893x over previous
//
#include <hip/hip_runtime.h>
#include <stdint.h>

#define B_ROWS 8192
#define P_ROWS 4096
#define D_DIM  1024
#define K_TOP  6

typedef __attribute__((ext_vector_type(8))) short short8;
typedef __attribute__((ext_vector_type(4))) float floatx4;

static __device__ __forceinline__ float bf2f(unsigned short h) {
  return __uint_as_float(((unsigned)h) << 16);
}
static __device__ __forceinline__ unsigned short f2bf(float f) {
  unsigned u = __float_as_uint(f);
  u += 0x7FFFu + ((u >> 16) & 1u);   // RNE
  return (unsigned short)(u >> 16);
}

// ---------------- fused fp32 -> bf16 convert for all 8 tensors ----------------
// segments (element offsets, compile-time): query 8388608, bank 4194304, 6x weights 1048576
struct ConvArgs {
  const float* s[8];
  unsigned short* d[8];
};
#define SEG0_END  8388608u
#define SEG1_END 12582912u
#define CONV_TOTAL 18874368u

__global__ __launch_bounds__(256) void convert_all_kernel(ConvArgs a) {
  unsigned e = (blockIdx.x * 256u + threadIdx.x) * 4u;
  int seg; unsigned base;
  if (e < SEG0_END) { seg = 0; base = 0; }
  else if (e < SEG1_END) { seg = 1; base = SEG0_END; }
  else {
    unsigned w = e - SEG1_END;
    seg = 2 + (int)(w >> 20);
    base = SEG1_END + (((unsigned)(seg - 2)) << 20);
  }
  unsigned off = e - base;
  float4 v = *(const float4*)(a.s[seg] + off);
  ushort4 o;
  o.x = f2bf(v.x); o.y = f2bf(v.y); o.z = f2bf(v.z); o.w = f2bf(v.w);
  *(ushort4*)(a.d[seg] + off) = o;
}

// ---------------- top-6 of 4096 logits per row, one wave per row ----------------
// Streaming per-lane sorted top-6 (12 VGPRs of state; no spills), then wave merge.
static __device__ __forceinline__ void cswap64(unsigned long long& hi, unsigned long long& lo) {
  unsigned long long a = hi, b = lo;
  bool c = b > a;
  hi = c ? b : a;
  lo = c ? a : b;
}

__global__ __launch_bounds__(256) void topk6_kernel(const float* __restrict__ logits,
                                                    int* __restrict__ out) {
  const int wid = threadIdx.x >> 6;
  const int lane = threadIdx.x & 63;
  const int row = blockIdx.x * 4 + wid;
  const float4* lp4 = (const float4*)(logits + (size_t)row * P_ROWS);

  unsigned long long m0 = 0, m1 = 0, m2 = 0, m3 = 0, m4 = 0, m5 = 0;

  auto ins = [&](float val, int idx) {
    unsigned u = __float_as_uint(val);
    u ^= ((unsigned)((int)u >> 31)) | 0x80000000u;          // monotone order map
    unsigned long long key =
        (((unsigned long long)u) << 32) | (unsigned long long)(0xFFFFFFFFu - (unsigned)idx);
    m5 = key > m5 ? key : m5;                                // replace bottom
    cswap64(m4, m5);                                         // bubble up
    cswap64(m3, m4);
    cswap64(m2, m3);
    cswap64(m1, m2);
    cswap64(m0, m1);
  };

#pragma unroll
  for (int j = 0; j < 16; ++j) {
    float4 v = lp4[j * 64 + lane];
    const int base = j * 256 + lane * 4;
    ins(v.x, base);
    ins(v.y, base + 1);
    ins(v.z, base + 2);
    ins(v.w, base + 3);
  }

  // merge 64 per-lane sorted lists -> global top-6
#pragma unroll
  for (int it = 0; it < K_TOP; ++it) {
    unsigned long long best = m0;
#pragma unroll
    for (int o = 32; o > 0; o >>= 1) {
      unsigned long long t = __shfl_xor(best, o);
      best = t > best ? t : best;
    }
    if (lane == 0)
      out[row * K_TOP + it] = (int)(0xFFFFFFFFu - (unsigned)(best & 0xFFFFFFFFull));
    const bool pred = (m0 == best);
    m0 = pred ? m1 : m0;
    m1 = pred ? m2 : m1;
    m2 = pred ? m3 : m2;
    m3 = pred ? m4 : m3;
    m4 = pred ? m5 : m4;
    m5 = pred ? 0ull : m5;
  }
}

// ---------------- bf16 MFMA GEMM, C[m,n] = sum_d A[m,d]*W[n,d] + bias[n] ----------------
typedef __attribute__((address_space(3))) unsigned int lds32_t;
typedef const __attribute__((address_space(1))) unsigned int g32_t;

static __device__ __forceinline__ void gld_lds16(const unsigned short* g, unsigned short* l) {
  __builtin_amdgcn_global_load_lds((g32_t*)(uintptr_t)g,
                                   (lds32_t*)(unsigned int)(uintptr_t)l, 16, 0, 0);
}

template <bool OUT_BF16>
static __device__ __forceinline__ void gemm_bt_body(
    const unsigned short* __restrict__ A, const unsigned short* __restrict__ Bw,
    const float* __restrict__ bias, void* __restrict__ Cout, int m0, int n0) {
  constexpr int Kd = 1024, Nd = 1024, BK = 64;
  __shared__ unsigned short sA[128 * BK];
  __shared__ unsigned short sB[128 * BK];

  const int tid = threadIdx.x;
  const int wid = tid >> 6, lane = tid & 63;
  const int wm = (wid & 1) * 64, wn = (wid >> 1) * 64;

  floatx4 acc[4][4];
#pragma unroll
  for (int mt = 0; mt < 4; ++mt)
#pragma unroll
    for (int nt = 0; nt < 4; ++nt) acc[mt][nt] = (floatx4){0.f, 0.f, 0.f, 0.f};

  const int ld_row = lane >> 3;
  const int ld_col = (lane & 7) * 8;

  for (int kt = 0; kt < Kd / BK; ++kt) {
    const int k0 = kt * BK;
    __syncthreads();
#pragma unroll
    for (int c = 0; c < 4; ++c) {
      const int ch = wid * 4 + c;
      const int r = ch * 8 + ld_row;
      gld_lds16(A  + (size_t)(m0 + r) * Kd + k0 + ld_col, sA + ch * 512);
      gld_lds16(Bw + (size_t)(n0 + r) * Kd + k0 + ld_col, sB + ch * 512);
    }
    __syncthreads();
#pragma unroll
    for (int ks = 0; ks < 2; ++ks) {
      const int kk = ks * 32 + (lane >> 4) * 8;
      short8 a[4], b[4];
#pragma unroll
      for (int t = 0; t < 4; ++t) {
        a[t] = *(const short8*)(sA + (wm + t * 16 + (lane & 15)) * BK + kk);
        b[t] = *(const short8*)(sB + (wn + t * 16 + (lane & 15)) * BK + kk);
      }
#pragma unroll
      for (int mt = 0; mt < 4; ++mt)
#pragma unroll
        for (int nt = 0; nt < 4; ++nt)
          acc[mt][nt] = __builtin_amdgcn_mfma_f32_16x16x32_bf16(a[mt], b[nt], acc[mt][nt], 0, 0, 0);
    }
  }

  const int er = lane >> 4;   // C/D: row=(lane>>4)*4+reg, col=lane&15 (m89-verified)
  const int ec = lane & 15;
#pragma unroll
  for (int mt = 0; mt < 4; ++mt) {
#pragma unroll
    for (int nt = 0; nt < 4; ++nt) {
      const int col = n0 + wn + nt * 16 + ec;
      const float bv = bias[col];
#pragma unroll
      for (int r = 0; r < 4; ++r) {
        const int row = m0 + wm + mt * 16 + er * 4 + r;
        const float v = acc[mt][nt][r] + bv;
        if (OUT_BF16)
          ((unsigned short*)Cout)[(size_t)row * Nd + col] = f2bf(v);
        else
          ((float*)Cout)[(size_t)row * Nd + col] = v;
      }
    }
  }
}

template <bool OUT_BF16>
__global__ __launch_bounds__(256) void gemm_bt_kernel(
    const unsigned short* __restrict__ A, const unsigned short* __restrict__ Bw,
    const float* __restrict__ bias, void* __restrict__ Cout) {
  gemm_bt_body<OUT_BF16>(A, Bw, bias, Cout, blockIdx.y * 128, blockIdx.x * 128);
}

// two weight matrices sharing the same A (kb and vb from projected bank)
__global__ __launch_bounds__(256) void gemm_bt_dual_kernel(
    const unsigned short* __restrict__ A,
    const unsigned short* __restrict__ W0, const float* __restrict__ b0, unsigned short* C0,
    const unsigned short* __restrict__ W1, const float* __restrict__ b1, unsigned short* C1) {
  const unsigned short* Bw = blockIdx.z ? W1 : W0;
  const float* bias = blockIdx.z ? b1 : b0;
  unsigned short* C = blockIdx.z ? C1 : C0;
  gemm_bt_body<true>(A, Bw, bias, (void*)C, blockIdx.y * 128, blockIdx.x * 128);
}

// ---------------- attention: one block per row, one wave = one head-dim (64) ----------------
__global__ __launch_bounds__(256) void attn_kernel(
    const unsigned short* __restrict__ q2,  // [B,1024] bf16
    const unsigned short* __restrict__ kb,  // [P,1024] bf16
    const unsigned short* __restrict__ vb,  // [P,1024] bf16
    const int* __restrict__ topk,           // [B,6]
    unsigned short* __restrict__ ctx,       // [B,1024] bf16 out
    float* __restrict__ attnw) {            // [B,6] fp32 out
  const int b = blockIdx.x;
  const int wid = threadIdx.x >> 6, lane = threadIdx.x & 63;
  __shared__ float wsum[4][K_TOP];

  int idx[K_TOP];
#pragma unroll
  for (int j = 0; j < K_TOP; ++j) idx[j] = topk[b * K_TOP + j];

  float hw[K_TOP] = {0.f, 0.f, 0.f, 0.f, 0.f, 0.f};
#pragma unroll
  for (int hh = 0; hh < 4; ++hh) {
    const int h = wid * 4 + hh;
    const int off = h * 64 + lane;
    const float qv = bf2f(q2[(size_t)b * D_DIM + off]);
    float s[K_TOP];
#pragma unroll
    for (int j = 0; j < K_TOP; ++j)
      s[j] = qv * bf2f(kb[(size_t)idx[j] * D_DIM + off]);
#pragma unroll
    for (int j = 0; j < K_TOP; ++j)
#pragma unroll
      for (int o = 32; o > 0; o >>= 1) s[j] += __shfl_xor(s[j], o);

    float mx = -1e30f;
#pragma unroll
    for (int j = 0; j < K_TOP; ++j) mx = fmaxf(mx, s[j] * 0.125f);
    float e[K_TOP], sum = 0.f;
#pragma unroll
    for (int j = 0; j < K_TOP; ++j) { e[j] = __expf(s[j] * 0.125f - mx); sum += e[j]; }
    const float inv = 1.0f / sum;

    float o = 0.f;
#pragma unroll
    for (int j = 0; j < K_TOP; ++j) {
      const float w = e[j] * inv;
      hw[j] += w;
      o += w * bf2f(vb[(size_t)idx[j] * D_DIM + off]);
    }
    ctx[(size_t)b * D_DIM + off] = f2bf(o);
  }
  if (lane == 0) {
#pragma unroll
    for (int j = 0; j < K_TOP; ++j) wsum[wid][j] = hw[j];
  }
  __syncthreads();
  if (threadIdx.x < K_TOP) {
    const float t = wsum[0][threadIdx.x] + wsum[1][threadIdx.x] +
                    wsum[2][threadIdx.x] + wsum[3][threadIdx.x];
    attnw[(size_t)b * K_TOP + threadIdx.x] = t * (1.0f / 16.0f);
  }
}

extern "C" void kernel_launch(void* const* d_in, const int* in_sizes, int n_in,
                              void* d_out, int out_size, void* d_ws, size_t ws_size,
                              hipStream_t stream) {
  const float* query   = (const float*)d_in[0];
  const float* bank    = (const float*)d_in[1];
  const float* logits  = (const float*)d_in[2];
  const float* Wq_proj = (const float*)d_in[3];
  const float* bq_proj = (const float*)d_in[4];
  const float* Wp_proj = (const float*)d_in[5];
  const float* bp_proj = (const float*)d_in[6];
  const float* Wq      = (const float*)d_in[7];
  const float* bq      = (const float*)d_in[8];
  const float* Wk      = (const float*)d_in[9];
  const float* bk      = (const float*)d_in[10];
  const float* Wv      = (const float*)d_in[11];
  const float* bv      = (const float*)d_in[12];
  const float* Wo      = (const float*)d_in[13];
  const float* bo      = (const float*)d_in[14];

  char* ws = (char*)d_ws;
  size_t off = 0;
  auto alloc = [&](size_t bytes) {
    void* p = ws + off;
    off += (bytes + 255) & ~(size_t)255;
    return p;
  };
  unsigned short* q_bf    = (unsigned short*)alloc((size_t)B_ROWS * D_DIM * 2); // query, then q2
  unsigned short* bank_bf = (unsigned short*)alloc((size_t)P_ROWS * D_DIM * 2); // bank, then kb
  unsigned short* q1_bf   = (unsigned short*)alloc((size_t)B_ROWS * D_DIM * 2); // q1, then ctx
  unsigned short* pb_bf   = (unsigned short*)alloc((size_t)P_ROWS * D_DIM * 2);
  unsigned short* vb_bf   = (unsigned short*)alloc((size_t)P_ROWS * D_DIM * 2);
  unsigned short* wqp_bf  = (unsigned short*)alloc((size_t)D_DIM * D_DIM * 2);
  unsigned short* wpp_bf  = (unsigned short*)alloc((size_t)D_DIM * D_DIM * 2);
  unsigned short* wq_bf   = (unsigned short*)alloc((size_t)D_DIM * D_DIM * 2);
  unsigned short* wk_bf   = (unsigned short*)alloc((size_t)D_DIM * D_DIM * 2);
  unsigned short* wv_bf   = (unsigned short*)alloc((size_t)D_DIM * D_DIM * 2);
  unsigned short* wo_bf   = (unsigned short*)alloc((size_t)D_DIM * D_DIM * 2);
  int* topk               = (int*)alloc((size_t)B_ROWS * K_TOP * 4);

  float* out_ctx  = (float*)d_out;
  float* out_attn = out_ctx + (size_t)B_ROWS * D_DIM;

  ConvArgs ca;
  ca.s[0] = query;   ca.d[0] = q_bf;
  ca.s[1] = bank;    ca.d[1] = bank_bf;
  ca.s[2] = Wq_proj; ca.d[2] = wqp_bf;
  ca.s[3] = Wp_proj; ca.d[3] = wpp_bf;
  ca.s[4] = Wq;      ca.d[4] = wq_bf;
  ca.s[5] = Wk;      ca.d[5] = wk_bf;
  ca.s[6] = Wv;      ca.d[6] = wv_bf;
  ca.s[7] = Wo;      ca.d[7] = wo_bf;
  convert_all_kernel<<<CONV_TOTAL / 1024, 256, 0, stream>>>(ca);

  topk6_kernel<<<B_ROWS / 4, 256, 0, stream>>>(logits, topk);

  auto gemm_bf = [&](const unsigned short* A, const unsigned short* W, const float* bias,
                     unsigned short* C, int M) {
    dim3 grid(D_DIM / 128, M / 128);
    gemm_bt_kernel<true><<<grid, 256, 0, stream>>>(A, W, bias, (void*)C);
  };
  gemm_bf(q_bf,    wqp_bf, bq_proj, q1_bf, B_ROWS);   // q1
  gemm_bf(bank_bf, wpp_bf, bp_proj, pb_bf, P_ROWS);   // projected bank
  gemm_bf(q1_bf,   wq_bf,  bq,      q_bf,  B_ROWS);   // q2 (reuse q_bf)

  {
    dim3 grid(D_DIM / 128, P_ROWS / 128, 2);          // kb (z=0, into bank_bf) + vb (z=1)
    gemm_bt_dual_kernel<<<grid, 256, 0, stream>>>(pb_bf, wk_bf, bk, bank_bf, wv_bf, bv, vb_bf);
  }

  attn_kernel<<<B_ROWS, 256, 0, stream>>>(q_bf, bank_bf, vb_bf, topk, q1_bf, out_attn);

  dim3 grid2(D_DIM / 128, B_ROWS / 128);
  gemm_bt_kernel<false><<<grid2, 256, 0, stream>>>(q1_bf, wo_bf, bo, d_out);  // context
}

// Round 3
// 462.989 us; speedup vs baseline: 1.1251x; 1.0328x over previous
//
#include <hip/hip_runtime.h>
#include <stdint.h>

#define B_ROWS 8192
#define P_ROWS 4096
#define D_DIM  1024
#define K_TOP  6

typedef __attribute__((ext_vector_type(8))) short short8;
typedef __attribute__((ext_vector_type(4))) float floatx4;

static __device__ __forceinline__ float bf2f(unsigned short h) {
  return __uint_as_float(((unsigned)h) << 16);
}
static __device__ __forceinline__ unsigned short f2bf(float f) {
  unsigned u = __float_as_uint(f);
  u += 0x7FFFu + ((u >> 16) & 1u);   // RNE
  return (unsigned short)(u >> 16);
}

// ---------------- fused fp32 -> bf16 convert for all 8 tensors ----------------
struct ConvArgs {
  const float* s[8];
  unsigned short* d[8];
};
#define SEG0_END  8388608u
#define SEG1_END 12582912u
#define CONV_TOTAL 18874368u

__global__ __launch_bounds__(256) void convert_all_kernel(ConvArgs a) {
  unsigned e = (blockIdx.x * 256u + threadIdx.x) * 4u;
  int seg; unsigned base;
  if (e < SEG0_END) { seg = 0; base = 0; }
  else if (e < SEG1_END) { seg = 1; base = SEG0_END; }
  else {
    unsigned w = e - SEG1_END;
    seg = 2 + (int)(w >> 20);
    base = SEG1_END + (((unsigned)(seg - 2)) << 20);
  }
  unsigned off = e - base;
  float4 v = *(const float4*)(a.s[seg] + off);
  ushort4 o;
  o.x = f2bf(v.x); o.y = f2bf(v.y); o.z = f2bf(v.z); o.w = f2bf(v.w);
  *(ushort4*)(a.d[seg] + off) = o;
}

// ---------------- bf16 64x64-tile transpose (two tensors via blockIdx.z) ----------------
__global__ __launch_bounds__(256) void transpose2_kernel(
    const unsigned short* __restrict__ s0, unsigned short* __restrict__ d0,
    const unsigned short* __restrict__ s1, unsigned short* __restrict__ d1) {
  const unsigned short* src = blockIdx.z ? s1 : s0;
  unsigned short* dst = blockIdx.z ? d1 : d0;
  __shared__ unsigned short t[64][72];   // row stride 144 B (16B-aligned), breaks pow2 conflicts
  const int i0 = blockIdx.y * 64, j0 = blockIdx.x * 64;
  const int r = threadIdx.x >> 4;
  const int c = (threadIdx.x & 15) * 4;
#pragma unroll
  for (int rr = 0; rr < 4; ++rr) {
    const int row = r + rr * 16;
    ushort4 v = *(const ushort4*)(src + (size_t)(i0 + row) * D_DIM + j0 + c);
    t[c + 0][row] = v.x; t[c + 1][row] = v.y; t[c + 2][row] = v.z; t[c + 3][row] = v.w;
  }
  __syncthreads();
#pragma unroll
  for (int rr = 0; rr < 4; ++rr) {
    const int row = r + rr * 16;                 // = original col j0+row
    ushort4 v = *(const ushort4*)(&t[row][c]);
    *(ushort4*)(dst + (size_t)(j0 + row) * D_DIM + i0 + c) = v;
  }
}

// ---------------- fused bias: bc = W @ b_proj + b  (fp32, 3 jobs) ----------------
struct Bias3Args {
  const float* W[3];
  const float* p[3];
  const float* b[3];
  float* o[3];
};
__global__ __launch_bounds__(256) void bias3_kernel(Bias3Args a) {
  const int j = blockIdx.y;
  const int wid = threadIdx.x >> 6, lane = threadIdx.x & 63;
  const int n = blockIdx.x * 4 + wid;
  const float* W = a.W[j] + (size_t)n * D_DIM;
  const float* p = a.p[j];
  float s = 0.f;
#pragma unroll
  for (int d = lane; d < D_DIM; d += 64) s += W[d] * p[d];
#pragma unroll
  for (int o = 32; o > 0; o >>= 1) s += __shfl_xor(s, o);
  if (lane == 0) a.o[j][n] = s + a.b[j][n];
}

// ---------------- top-6 of 4096 logits per row, one wave per row ----------------
static __device__ __forceinline__ void cswap64(unsigned long long& hi, unsigned long long& lo) {
  unsigned long long a = hi, b = lo;
  bool c = b > a;
  hi = c ? b : a;
  lo = c ? a : b;
}

__global__ __launch_bounds__(256) void topk6_kernel(const float* __restrict__ logits,
                                                    int* __restrict__ out) {
  const int wid = threadIdx.x >> 6;
  const int lane = threadIdx.x & 63;
  const int row = blockIdx.x * 4 + wid;
  const float4* lp4 = (const float4*)(logits + (size_t)row * P_ROWS);

  unsigned long long m0 = 0, m1 = 0, m2 = 0, m3 = 0, m4 = 0, m5 = 0;

  auto ins = [&](float val, int idx) {
    unsigned u = __float_as_uint(val);
    u ^= ((unsigned)((int)u >> 31)) | 0x80000000u;   // monotone order map
    unsigned long long key =
        (((unsigned long long)u) << 32) | (unsigned long long)(0xFFFFFFFFu - (unsigned)idx);
    m5 = key > m5 ? key : m5;
    cswap64(m4, m5);
    cswap64(m3, m4);
    cswap64(m2, m3);
    cswap64(m1, m2);
    cswap64(m0, m1);
  };

#pragma unroll
  for (int j = 0; j < 16; ++j) {
    float4 v = lp4[j * 64 + lane];
    const int base = j * 256 + lane * 4;
    ins(v.x, base);
    ins(v.y, base + 1);
    ins(v.z, base + 2);
    ins(v.w, base + 3);
  }

#pragma unroll
  for (int it = 0; it < K_TOP; ++it) {
    unsigned long long best = m0;
#pragma unroll
    for (int o = 32; o > 0; o >>= 1) {
      unsigned long long t = __shfl_xor(best, o);
      best = t > best ? t : best;
    }
    if (lane == 0)
      out[row * K_TOP + it] = (int)(0xFFFFFFFFu - (unsigned)(best & 0xFFFFFFFFull));
    const bool pred = (m0 == best);
    m0 = pred ? m1 : m0;
    m1 = pred ? m2 : m1;
    m2 = pred ? m3 : m2;
    m3 = pred ? m4 : m3;
    m4 = pred ? m5 : m4;
    m5 = pred ? 0ull : m5;
  }
}

// ---------------- bf16 MFMA GEMM, C[m,n] = sum_d A[m,d]*W[n,d] (+ bias[n]) ----------------
typedef __attribute__((address_space(3))) unsigned int lds32_t;
typedef const __attribute__((address_space(1))) unsigned int g32_t;

static __device__ __forceinline__ void gld_lds16(const unsigned short* g, unsigned short* l) {
  __builtin_amdgcn_global_load_lds((g32_t*)(uintptr_t)g,
                                   (lds32_t*)(unsigned int)(uintptr_t)l, 16, 0, 0);
}

template <bool OUT_BF16, bool HAS_BIAS>
static __device__ __forceinline__ void gemm_bt_body(
    const unsigned short* __restrict__ A, const unsigned short* __restrict__ Bw,
    const float* __restrict__ bias, void* __restrict__ Cout, int m0, int n0) {
  constexpr int Kd = 1024, Nd = 1024, BK = 64;
  __shared__ unsigned short sA[128 * BK];
  __shared__ unsigned short sB[128 * BK];

  const int tid = threadIdx.x;
  const int wid = tid >> 6, lane = tid & 63;
  const int wm = (wid & 1) * 64, wn = (wid >> 1) * 64;

  floatx4 acc[4][4];
#pragma unroll
  for (int mt = 0; mt < 4; ++mt)
#pragma unroll
    for (int nt = 0; nt < 4; ++nt) acc[mt][nt] = (floatx4){0.f, 0.f, 0.f, 0.f};

  const int ld_row = lane >> 3;
  const int ld_col = (lane & 7) * 8;

  for (int kt = 0; kt < Kd / BK; ++kt) {
    const int k0 = kt * BK;
    __syncthreads();
#pragma unroll
    for (int c = 0; c < 4; ++c) {
      const int ch = wid * 4 + c;
      const int r = ch * 8 + ld_row;
      gld_lds16(A  + (size_t)(m0 + r) * Kd + k0 + ld_col, sA + ch * 512);
      gld_lds16(Bw + (size_t)(n0 + r) * Kd + k0 + ld_col, sB + ch * 512);
    }
    __syncthreads();
#pragma unroll
    for (int ks = 0; ks < 2; ++ks) {
      const int kk = ks * 32 + (lane >> 4) * 8;
      short8 a[4], b[4];
#pragma unroll
      for (int t = 0; t < 4; ++t) {
        a[t] = *(const short8*)(sA + (wm + t * 16 + (lane & 15)) * BK + kk);
        b[t] = *(const short8*)(sB + (wn + t * 16 + (lane & 15)) * BK + kk);
      }
#pragma unroll
      for (int mt = 0; mt < 4; ++mt)
#pragma unroll
        for (int nt = 0; nt < 4; ++nt)
          acc[mt][nt] = __builtin_amdgcn_mfma_f32_16x16x32_bf16(a[mt], b[nt], acc[mt][nt], 0, 0, 0);
    }
  }

  const int er = lane >> 4;   // C/D: row=(lane>>4)*4+reg, col=lane&15 (m89-verified)
  const int ec = lane & 15;
#pragma unroll
  for (int mt = 0; mt < 4; ++mt) {
#pragma unroll
    for (int nt = 0; nt < 4; ++nt) {
      const int col = n0 + wn + nt * 16 + ec;
      const float bv = HAS_BIAS ? bias[col] : 0.f;
#pragma unroll
      for (int r = 0; r < 4; ++r) {
        const int row = m0 + wm + mt * 16 + er * 4 + r;
        const float v = acc[mt][nt][r] + bv;
        if (OUT_BF16)
          ((unsigned short*)Cout)[(size_t)row * Nd + col] = f2bf(v);
        else
          ((float*)Cout)[(size_t)row * Nd + col] = v;
      }
    }
  }
}

template <bool OUT_BF16>
__global__ __launch_bounds__(256) void gemm_bt_kernel(
    const unsigned short* __restrict__ A, const unsigned short* __restrict__ Bw,
    const float* __restrict__ bias, void* __restrict__ Cout) {
  gemm_bt_body<OUT_BF16, true>(A, Bw, bias, Cout, blockIdx.y * 128, blockIdx.x * 128);
}

// two weight matrices sharing the same A (kb and vb from bank)
__global__ __launch_bounds__(256) void gemm_bt_dual_kernel(
    const unsigned short* __restrict__ A,
    const unsigned short* __restrict__ W0, const float* __restrict__ b0, unsigned short* C0,
    const unsigned short* __restrict__ W1, const float* __restrict__ b1, unsigned short* C1) {
  const unsigned short* Bw = blockIdx.z ? W1 : W0;
  const float* bias = blockIdx.z ? b1 : b0;
  unsigned short* C = blockIdx.z ? C1 : C0;
  gemm_bt_body<true, true>(A, Bw, bias, (void*)C, blockIdx.y * 128, blockIdx.x * 128);
}

// three independent 1024^3 weight-fusion GEMMs (Wc = Wx @ Wproj), no bias
struct Fuse3Args {
  const unsigned short* A[3];
  const unsigned short* W[3];
  unsigned short* C[3];
};
__global__ __launch_bounds__(256) void gemm_fuse3_kernel(Fuse3Args a) {
  const int z = blockIdx.z;
  gemm_bt_body<true, false>(a.A[z], a.W[z], nullptr, (void*)a.C[z],
                            blockIdx.y * 128, blockIdx.x * 128);
}

// ---------------- attention: one block per row, one wave = one head-dim (64) ----------------
__global__ __launch_bounds__(256) void attn_kernel(
    const unsigned short* __restrict__ q2,  // [B,1024] bf16
    const unsigned short* __restrict__ kb,  // [P,1024] bf16
    const unsigned short* __restrict__ vb,  // [P,1024] bf16
    const int* __restrict__ topk,           // [B,6]
    unsigned short* __restrict__ ctx,       // [B,1024] bf16 out
    float* __restrict__ attnw) {            // [B,6] fp32 out
  const int b = blockIdx.x;
  const int wid = threadIdx.x >> 6, lane = threadIdx.x & 63;
  __shared__ float wsum[4][K_TOP];

  int idx[K_TOP];
#pragma unroll
  for (int j = 0; j < K_TOP; ++j) idx[j] = topk[b * K_TOP + j];

  float hw[K_TOP] = {0.f, 0.f, 0.f, 0.f, 0.f, 0.f};
#pragma unroll
  for (int hh = 0; hh < 4; ++hh) {
    const int h = wid * 4 + hh;
    const int off = h * 64 + lane;
    const float qv = bf2f(q2[(size_t)b * D_DIM + off]);
    float s[K_TOP];
#pragma unroll
    for (int j = 0; j < K_TOP; ++j)
      s[j] = qv * bf2f(kb[(size_t)idx[j] * D_DIM + off]);
#pragma unroll
    for (int j = 0; j < K_TOP; ++j)
#pragma unroll
      for (int o = 32; o > 0; o >>= 1) s[j] += __shfl_xor(s[j], o);

    float mx = -1e30f;
#pragma unroll
    for (int j = 0; j < K_TOP; ++j) mx = fmaxf(mx, s[j] * 0.125f);
    float e[K_TOP], sum = 0.f;
#pragma unroll
    for (int j = 0; j < K_TOP; ++j) { e[j] = __expf(s[j] * 0.125f - mx); sum += e[j]; }
    const float inv = 1.0f / sum;

    float o = 0.f;
#pragma unroll
    for (int j = 0; j < K_TOP; ++j) {
      const float w = e[j] * inv;
      hw[j] += w;
      o += w * bf2f(vb[(size_t)idx[j] * D_DIM + off]);
    }
    ctx[(size_t)b * D_DIM + off] = f2bf(o);
  }
  if (lane == 0) {
#pragma unroll
    for (int j = 0; j < K_TOP; ++j) wsum[wid][j] = hw[j];
  }
  __syncthreads();
  if (threadIdx.x < K_TOP) {
    const float t = wsum[0][threadIdx.x] + wsum[1][threadIdx.x] +
                    wsum[2][threadIdx.x] + wsum[3][threadIdx.x];
    attnw[(size_t)b * K_TOP + threadIdx.x] = t * (1.0f / 16.0f);
  }
}

extern "C" void kernel_launch(void* const* d_in, const int* in_sizes, int n_in,
                              void* d_out, int out_size, void* d_ws, size_t ws_size,
                              hipStream_t stream) {
  const float* query   = (const float*)d_in[0];
  const float* bank    = (const float*)d_in[1];
  const float* logits  = (const float*)d_in[2];
  const float* Wq_proj = (const float*)d_in[3];
  const float* bq_proj = (const float*)d_in[4];
  const float* Wp_proj = (const float*)d_in[5];
  const float* bp_proj = (const float*)d_in[6];
  const float* Wq      = (const float*)d_in[7];
  const float* bq      = (const float*)d_in[8];
  const float* Wk      = (const float*)d_in[9];
  const float* bk      = (const float*)d_in[10];
  const float* Wv      = (const float*)d_in[11];
  const float* bv      = (const float*)d_in[12];
  const float* Wo      = (const float*)d_in[13];
  const float* bo      = (const float*)d_in[14];

  char* ws = (char*)d_ws;
  size_t off = 0;
  auto alloc = [&](size_t bytes) {
    void* p = ws + off;
    off += (bytes + 255) & ~(size_t)255;
    return p;
  };
  unsigned short* q_bf    = (unsigned short*)alloc((size_t)B_ROWS * D_DIM * 2); // query, then ctx
  unsigned short* bank_bf = (unsigned short*)alloc((size_t)P_ROWS * D_DIM * 2);
  unsigned short* q2_bf   = (unsigned short*)alloc((size_t)B_ROWS * D_DIM * 2);
  unsigned short* kb_bf   = (unsigned short*)alloc((size_t)P_ROWS * D_DIM * 2);
  unsigned short* vb_bf   = (unsigned short*)alloc((size_t)P_ROWS * D_DIM * 2);
  unsigned short* wqp_bf  = (unsigned short*)alloc((size_t)D_DIM * D_DIM * 2);
  unsigned short* wpp_bf  = (unsigned short*)alloc((size_t)D_DIM * D_DIM * 2);
  unsigned short* wq_bf   = (unsigned short*)alloc((size_t)D_DIM * D_DIM * 2);
  unsigned short* wk_bf   = (unsigned short*)alloc((size_t)D_DIM * D_DIM * 2);
  unsigned short* wv_bf   = (unsigned short*)alloc((size_t)D_DIM * D_DIM * 2);
  unsigned short* wo_bf   = (unsigned short*)alloc((size_t)D_DIM * D_DIM * 2);
  unsigned short* wqpT_bf = (unsigned short*)alloc((size_t)D_DIM * D_DIM * 2);
  unsigned short* wppT_bf = (unsigned short*)alloc((size_t)D_DIM * D_DIM * 2);
  unsigned short* wcq_bf  = (unsigned short*)alloc((size_t)D_DIM * D_DIM * 2);
  unsigned short* wck_bf  = (unsigned short*)alloc((size_t)D_DIM * D_DIM * 2);
  unsigned short* wcv_bf  = (unsigned short*)alloc((size_t)D_DIM * D_DIM * 2);
  float* bcq              = (float*)alloc(D_DIM * 4);
  float* bck              = (float*)alloc(D_DIM * 4);
  float* bcv              = (float*)alloc(D_DIM * 4);
  int* topk               = (int*)alloc((size_t)B_ROWS * K_TOP * 4);

  float* out_ctx  = (float*)d_out;
  float* out_attn = out_ctx + (size_t)B_ROWS * D_DIM;

  // 1. convert fp32 -> bf16
  ConvArgs ca;
  ca.s[0] = query;   ca.d[0] = q_bf;
  ca.s[1] = bank;    ca.d[1] = bank_bf;
  ca.s[2] = Wq_proj; ca.d[2] = wqp_bf;
  ca.s[3] = Wp_proj; ca.d[3] = wpp_bf;
  ca.s[4] = Wq;      ca.d[4] = wq_bf;
  ca.s[5] = Wk;      ca.d[5] = wk_bf;
  ca.s[6] = Wv;      ca.d[6] = wv_bf;
  ca.s[7] = Wo;      ca.d[7] = wo_bf;
  convert_all_kernel<<<CONV_TOTAL / 1024, 256, 0, stream>>>(ca);

  // 2. transpose projection weights (for the NT side of the weight fusion)
  {
    dim3 grid(D_DIM / 64, D_DIM / 64, 2);
    transpose2_kernel<<<grid, 256, 0, stream>>>(wqp_bf, wqpT_bf, wpp_bf, wppT_bf);
  }

  // 3. fused weights: Wcq = Wq@Wqp, Wck = Wk@Wpp, Wcv = Wv@Wpp
  {
    Fuse3Args fa;
    fa.A[0] = wq_bf; fa.W[0] = wqpT_bf; fa.C[0] = wcq_bf;
    fa.A[1] = wk_bf; fa.W[1] = wppT_bf; fa.C[1] = wck_bf;
    fa.A[2] = wv_bf; fa.W[2] = wppT_bf; fa.C[2] = wcv_bf;
    dim3 grid(D_DIM / 128, D_DIM / 128, 3);
    gemm_fuse3_kernel<<<grid, 256, 0, stream>>>(fa);
  }

  // 4. fused biases (fp32, from original fp32 inputs): bc = W@b_proj + b
  {
    Bias3Args ba;
    ba.W[0] = Wq; ba.p[0] = bq_proj; ba.b[0] = bq; ba.o[0] = bcq;
    ba.W[1] = Wk; ba.p[1] = bp_proj; ba.b[1] = bk; ba.o[1] = bck;
    ba.W[2] = Wv; ba.p[2] = bp_proj; ba.b[2] = bv; ba.o[2] = bcv;
    dim3 grid(D_DIM / 4, 3);
    bias3_kernel<<<grid, 256, 0, stream>>>(ba);
  }

  // 5. top-k
  topk6_kernel<<<B_ROWS / 4, 256, 0, stream>>>(logits, topk);

  // 6. q2 = query @ Wcq^T + bcq
  {
    dim3 grid(D_DIM / 128, B_ROWS / 128);
    gemm_bt_kernel<true><<<grid, 256, 0, stream>>>(q_bf, wcq_bf, bcq, (void*)q2_bf);
  }

  // 7. kb/vb = bank @ {Wck,Wcv}^T + {bck,bcv}
  {
    dim3 grid(D_DIM / 128, P_ROWS / 128, 2);
    gemm_bt_dual_kernel<<<grid, 256, 0, stream>>>(bank_bf, wck_bf, bck, kb_bf,
                                                  wcv_bf, bcv, vb_bf);
  }

  // 8. attention (ctx into q_bf, which is free now)
  attn_kernel<<<B_ROWS, 256, 0, stream>>>(q2_bf, kb_bf, vb_bf, topk, q_bf, out_attn);

  // 9. context = ctx @ Wo^T + bo (fp32 out)
  {
    dim3 grid(D_DIM / 128, B_ROWS / 128);
    gemm_bt_kernel<false><<<grid, 256, 0, stream>>>(q_bf, wo_bf, bo, d_out);
  }
}

// Round 4
// 443.580 us; speedup vs baseline: 1.1743x; 1.0438x over previous
//
#include <hip/hip_runtime.h>
#include <stdint.h>

#define B_ROWS 8192
#define P_ROWS 4096
#define D_DIM  1024
#define K_TOP  6

typedef __attribute__((ext_vector_type(8))) short short8;
typedef __attribute__((ext_vector_type(4))) float floatx4;

static __device__ __forceinline__ float bf2f(unsigned short h) {
  return __uint_as_float(((unsigned)h) << 16);
}
static __device__ __forceinline__ unsigned short f2bf(float f) {
  unsigned u = __float_as_uint(f);
  u += 0x7FFFu + ((u >> 16) & 1u);   // RNE
  return (unsigned short)(u >> 16);
}

// ---------------- bf16 MFMA GEMM body, C[m,n] = sum_d A[m,d]*W[n,d] (+ bias[n]) ----------------
typedef __attribute__((address_space(3))) unsigned int lds32_t;
typedef const __attribute__((address_space(1))) unsigned int g32_t;

static __device__ __forceinline__ void gld_lds16(const unsigned short* g, unsigned short* l) {
  __builtin_amdgcn_global_load_lds((g32_t*)(uintptr_t)g,
                                   (lds32_t*)(unsigned int)(uintptr_t)l, 16, 0, 0);
}

template <bool OUT_BF16, bool HAS_BIAS>
static __device__ __forceinline__ void gemm_bt_body(
    const unsigned short* __restrict__ A, const unsigned short* __restrict__ Bw,
    const float* __restrict__ bias, void* __restrict__ Cout, int m0, int n0) {
  constexpr int Kd = 1024, Nd = 1024, BK = 64;
  __shared__ unsigned short sA[128 * BK];
  __shared__ unsigned short sB[128 * BK];

  const int tid = threadIdx.x;
  const int wid = tid >> 6, lane = tid & 63;
  const int wm = (wid & 1) * 64, wn = (wid >> 1) * 64;

  floatx4 acc[4][4];
#pragma unroll
  for (int mt = 0; mt < 4; ++mt)
#pragma unroll
    for (int nt = 0; nt < 4; ++nt) acc[mt][nt] = (floatx4){0.f, 0.f, 0.f, 0.f};

  const int ld_row = lane >> 3;
  const int ld_col = (lane & 7) * 8;

  for (int kt = 0; kt < Kd / BK; ++kt) {
    const int k0 = kt * BK;
    __syncthreads();
#pragma unroll
    for (int c = 0; c < 4; ++c) {
      const int ch = wid * 4 + c;
      const int r = ch * 8 + ld_row;
      gld_lds16(A  + (size_t)(m0 + r) * Kd + k0 + ld_col, sA + ch * 512);
      gld_lds16(Bw + (size_t)(n0 + r) * Kd + k0 + ld_col, sB + ch * 512);
    }
    __syncthreads();
#pragma unroll
    for (int ks = 0; ks < 2; ++ks) {
      const int kk = ks * 32 + (lane >> 4) * 8;
      short8 a[4], b[4];
#pragma unroll
      for (int t = 0; t < 4; ++t) {
        a[t] = *(const short8*)(sA + (wm + t * 16 + (lane & 15)) * BK + kk);
        b[t] = *(const short8*)(sB + (wn + t * 16 + (lane & 15)) * BK + kk);
      }
#pragma unroll
      for (int mt = 0; mt < 4; ++mt)
#pragma unroll
        for (int nt = 0; nt < 4; ++nt)
          acc[mt][nt] = __builtin_amdgcn_mfma_f32_16x16x32_bf16(a[mt], b[nt], acc[mt][nt], 0, 0, 0);
    }
  }

  const int er = lane >> 4;   // C/D: row=(lane>>4)*4+reg, col=lane&15 (m89-verified)
  const int ec = lane & 15;
#pragma unroll
  for (int mt = 0; mt < 4; ++mt) {
#pragma unroll
    for (int nt = 0; nt < 4; ++nt) {
      const int col = n0 + wn + nt * 16 + ec;
      const float bv = HAS_BIAS ? bias[col] : 0.f;
#pragma unroll
      for (int r = 0; r < 4; ++r) {
        const int row = m0 + wm + mt * 16 + er * 4 + r;
        const float v = acc[mt][nt][r] + bv;
        if (OUT_BF16)
          ((unsigned short*)Cout)[(size_t)row * Nd + col] = f2bf(v);
        else
          ((float*)Cout)[(size_t)row * Nd + col] = v;
      }
    }
  }
}

template <bool OUT_BF16>
__global__ __launch_bounds__(256) void gemm_bt_kernel(
    const unsigned short* __restrict__ A, const unsigned short* __restrict__ Bw,
    const float* __restrict__ bias, void* __restrict__ Cout) {
  gemm_bt_body<OUT_BF16, true>(A, Bw, bias, Cout, blockIdx.y * 128, blockIdx.x * 128);
}

// ================= Phase A: conv6 + transposed-convert(Wqp,Wpp) + fused bias =================
// blocks [0,16384): fp32->bf16 convert {query 8192, bank 4096, Wq/Wk/Wv/Wo 1024 each}
// blocks [16384,16896): fp32->bf16 transpose of Wq_proj / Wp_proj (64x64 tiles)
// blocks [16896,17664): bc = W @ b_proj + b  (3 x 256 blocks, fp32)
#define PREP_BLOCKS 17664
struct PrepArgs {
  const float* cs[6]; unsigned short* cd[6];
  const float* ts[2]; unsigned short* td[2];
  const float* bW[3]; const float* bp[3]; const float* bb[3]; float* bo[3];
};

__global__ __launch_bounds__(256) void prep_kernel(PrepArgs a) {
  const int b = blockIdx.x;
  if (b < 16384) {
    int seg; unsigned sb;
    if (b < 8192) { seg = 0; sb = 0; }
    else if (b < 12288) { seg = 1; sb = 8192; }
    else { seg = 2 + ((b - 12288) >> 10); sb = 12288u + (((unsigned)(seg - 2)) << 10); }
    const unsigned off = (((unsigned)b - sb) << 10) + threadIdx.x * 4u;
    float4 v = *(const float4*)(a.cs[seg] + off);
    ushort4 o;
    o.x = f2bf(v.x); o.y = f2bf(v.y); o.z = f2bf(v.z); o.w = f2bf(v.w);
    *(ushort4*)(a.cd[seg] + off) = o;
  } else if (b < 16896) {
    __shared__ unsigned short t[64][72];
    const int tt = b - 16384;
    const int which = tt >> 8;
    const int tile = tt & 255;
    const int i0 = (tile >> 4) * 64, j0 = (tile & 15) * 64;
    const float* src = a.ts[which];
    unsigned short* dst = a.td[which];
    const int r = threadIdx.x >> 4;
    const int c = (threadIdx.x & 15) * 4;
#pragma unroll
    for (int rr = 0; rr < 4; ++rr) {
      const int row = r + rr * 16;
      float4 v = *(const float4*)(src + (size_t)(i0 + row) * D_DIM + j0 + c);
      t[c + 0][row] = f2bf(v.x); t[c + 1][row] = f2bf(v.y);
      t[c + 2][row] = f2bf(v.z); t[c + 3][row] = f2bf(v.w);
    }
    __syncthreads();
#pragma unroll
    for (int rr = 0; rr < 4; ++rr) {
      const int row = r + rr * 16;
      ushort4 v = *(const ushort4*)(&t[row][c]);
      *(ushort4*)(dst + (size_t)(j0 + row) * D_DIM + i0 + c) = v;
    }
  } else {
    const int b3 = b - 16896;
    const int j = b3 >> 8;
    const int nb = b3 & 255;
    const int wid = threadIdx.x >> 6, lane = threadIdx.x & 63;
    const int n = nb * 4 + wid;
    const float* W = a.bW[j] + (size_t)n * D_DIM;
    const float* p = a.bp[j];
    float s = 0.f;
#pragma unroll
    for (int d = lane; d < D_DIM; d += 64) s += W[d] * p[d];
#pragma unroll
    for (int o = 32; o > 0; o >>= 1) s += __shfl_xor(s, o);
    if (lane == 0) a.bo[j][n] = s + a.bb[j][n];
  }
}

// ================= Phase B: weight-fusion GEMMs (MFMA) overlapped with topk (VALU) =================
// blocks [0,192): Wc = Wx @ WprojT (3 x 64 tiles, no bias)
// blocks [192,2240): top-6 of 4096 logits, one wave per row
#define MID_BLOCKS 2240
struct MidArgs {
  const unsigned short* fA[3]; const unsigned short* fW[3]; unsigned short* fC[3];
  const float* logits; int* topk;
};

static __device__ __forceinline__ void cswap64(unsigned long long& hi, unsigned long long& lo) {
  unsigned long long x = hi, y = lo;
  bool c = y > x;
  hi = c ? y : x;
  lo = c ? x : y;
}

__global__ __launch_bounds__(256) void mid_kernel(MidArgs a) {
  const int b = blockIdx.x;
  if (b < 192) {
    const int z = b >> 6;
    const int tile = b & 63;
    gemm_bt_body<true, false>(a.fA[z], a.fW[z], nullptr, (void*)a.fC[z],
                              (tile >> 3) * 128, (tile & 7) * 128);
    return;
  }
  const int wid = threadIdx.x >> 6;
  const int lane = threadIdx.x & 63;
  const int row = (b - 192) * 4 + wid;
  const float4* lp4 = (const float4*)(a.logits + (size_t)row * P_ROWS);

  unsigned long long m0 = 0, m1 = 0, m2 = 0, m3 = 0, m4 = 0, m5 = 0;
  auto ins = [&](float val, int idx) {
    unsigned u = __float_as_uint(val);
    u ^= ((unsigned)((int)u >> 31)) | 0x80000000u;   // monotone order map
    unsigned long long key =
        (((unsigned long long)u) << 32) | (unsigned long long)(0xFFFFFFFFu - (unsigned)idx);
    m5 = key > m5 ? key : m5;
    cswap64(m4, m5);
    cswap64(m3, m4);
    cswap64(m2, m3);
    cswap64(m1, m2);
    cswap64(m0, m1);
  };
#pragma unroll
  for (int j = 0; j < 16; ++j) {
    float4 v = lp4[j * 64 + lane];
    const int base = j * 256 + lane * 4;
    ins(v.x, base);
    ins(v.y, base + 1);
    ins(v.z, base + 2);
    ins(v.w, base + 3);
  }
#pragma unroll
  for (int it = 0; it < K_TOP; ++it) {
    unsigned long long best = m0;
#pragma unroll
    for (int o = 32; o > 0; o >>= 1) {
      unsigned long long t = __shfl_xor(best, o);
      best = t > best ? t : best;
    }
    if (lane == 0)
      a.topk[row * K_TOP + it] = (int)(0xFFFFFFFFu - (unsigned)(best & 0xFFFFFFFFull));
    const bool pred = (m0 == best);
    m0 = pred ? m1 : m0;
    m1 = pred ? m2 : m1;
    m2 = pred ? m3 : m2;
    m3 = pred ? m4 : m3;
    m4 = pred ? m5 : m4;
    m5 = pred ? 0ull : m5;
  }
}

// ================= Phase C: three production GEMMs in one launch =================
// blocks [0,512): q2 = query@Wcq^T+bcq (M=8192); [512,768): kb (M=4096); [768,1024): vb
#define GEMM3_BLOCKS 1024
struct Gemm3Args {
  const unsigned short* A[3]; const unsigned short* W[3]; const float* bias[3];
  unsigned short* C[3];
};

__global__ __launch_bounds__(256) void gemm3_kernel(Gemm3Args a) {
  const int b = blockIdx.x;
  int seg, lb;
  if (b < 512) { seg = 0; lb = b; }
  else if (b < 768) { seg = 1; lb = b - 512; }
  else { seg = 2; lb = b - 768; }
  gemm_bt_body<true, true>(a.A[seg], a.W[seg], a.bias[seg], (void*)a.C[seg],
                           (lb >> 3) * 128, (lb & 7) * 128);
}

// ================= attention: one block per row, one wave = one head-dim (64) =================
__global__ __launch_bounds__(256) void attn_kernel(
    const unsigned short* __restrict__ q2,
    const unsigned short* __restrict__ kb,
    const unsigned short* __restrict__ vb,
    const int* __restrict__ topk,
    unsigned short* __restrict__ ctx,
    float* __restrict__ attnw) {
  const int b = blockIdx.x;
  const int wid = threadIdx.x >> 6, lane = threadIdx.x & 63;
  __shared__ float wsum[4][K_TOP];

  int idx[K_TOP];
#pragma unroll
  for (int j = 0; j < K_TOP; ++j) idx[j] = topk[b * K_TOP + j];

  float hw[K_TOP] = {0.f, 0.f, 0.f, 0.f, 0.f, 0.f};
#pragma unroll
  for (int hh = 0; hh < 4; ++hh) {
    const int h = wid * 4 + hh;
    const int off = h * 64 + lane;
    const float qv = bf2f(q2[(size_t)b * D_DIM + off]);
    float s[K_TOP];
#pragma unroll
    for (int j = 0; j < K_TOP; ++j)
      s[j] = qv * bf2f(kb[(size_t)idx[j] * D_DIM + off]);
#pragma unroll
    for (int j = 0; j < K_TOP; ++j)
#pragma unroll
      for (int o = 32; o > 0; o >>= 1) s[j] += __shfl_xor(s[j], o);

    float mx = -1e30f;
#pragma unroll
    for (int j = 0; j < K_TOP; ++j) mx = fmaxf(mx, s[j] * 0.125f);
    float e[K_TOP], sum = 0.f;
#pragma unroll
    for (int j = 0; j < K_TOP; ++j) { e[j] = __expf(s[j] * 0.125f - mx); sum += e[j]; }
    const float inv = 1.0f / sum;

    float o = 0.f;
#pragma unroll
    for (int j = 0; j < K_TOP; ++j) {
      const float w = e[j] * inv;
      hw[j] += w;
      o += w * bf2f(vb[(size_t)idx[j] * D_DIM + off]);
    }
    ctx[(size_t)b * D_DIM + off] = f2bf(o);
  }
  if (lane == 0) {
#pragma unroll
    for (int j = 0; j < K_TOP; ++j) wsum[wid][j] = hw[j];
  }
  __syncthreads();
  if (threadIdx.x < K_TOP) {
    const float t = wsum[0][threadIdx.x] + wsum[1][threadIdx.x] +
                    wsum[2][threadIdx.x] + wsum[3][threadIdx.x];
    attnw[(size_t)b * K_TOP + threadIdx.x] = t * (1.0f / 16.0f);
  }
}

extern "C" void kernel_launch(void* const* d_in, const int* in_sizes, int n_in,
                              void* d_out, int out_size, void* d_ws, size_t ws_size,
                              hipStream_t stream) {
  const float* query   = (const float*)d_in[0];
  const float* bank    = (const float*)d_in[1];
  const float* logits  = (const float*)d_in[2];
  const float* Wq_proj = (const float*)d_in[3];
  const float* bq_proj = (const float*)d_in[4];
  const float* Wp_proj = (const float*)d_in[5];
  const float* bp_proj = (const float*)d_in[6];
  const float* Wq      = (const float*)d_in[7];
  const float* bq      = (const float*)d_in[8];
  const float* Wk      = (const float*)d_in[9];
  const float* bk      = (const float*)d_in[10];
  const float* Wv      = (const float*)d_in[11];
  const float* bv      = (const float*)d_in[12];
  const float* Wo      = (const float*)d_in[13];
  const float* bo      = (const float*)d_in[14];

  char* ws = (char*)d_ws;
  size_t off = 0;
  auto alloc = [&](size_t bytes) {
    void* p = ws + off;
    off += (bytes + 255) & ~(size_t)255;
    return p;
  };
  unsigned short* q_bf    = (unsigned short*)alloc((size_t)B_ROWS * D_DIM * 2); // query, then ctx
  unsigned short* bank_bf = (unsigned short*)alloc((size_t)P_ROWS * D_DIM * 2);
  unsigned short* q2_bf   = (unsigned short*)alloc((size_t)B_ROWS * D_DIM * 2);
  unsigned short* kb_bf   = (unsigned short*)alloc((size_t)P_ROWS * D_DIM * 2);
  unsigned short* vb_bf   = (unsigned short*)alloc((size_t)P_ROWS * D_DIM * 2);
  unsigned short* wq_bf   = (unsigned short*)alloc((size_t)D_DIM * D_DIM * 2);
  unsigned short* wk_bf   = (unsigned short*)alloc((size_t)D_DIM * D_DIM * 2);
  unsigned short* wv_bf   = (unsigned short*)alloc((size_t)D_DIM * D_DIM * 2);
  unsigned short* wo_bf   = (unsigned short*)alloc((size_t)D_DIM * D_DIM * 2);
  unsigned short* wqpT_bf = (unsigned short*)alloc((size_t)D_DIM * D_DIM * 2);
  unsigned short* wppT_bf = (unsigned short*)alloc((size_t)D_DIM * D_DIM * 2);
  unsigned short* wcq_bf  = (unsigned short*)alloc((size_t)D_DIM * D_DIM * 2);
  unsigned short* wck_bf  = (unsigned short*)alloc((size_t)D_DIM * D_DIM * 2);
  unsigned short* wcv_bf  = (unsigned short*)alloc((size_t)D_DIM * D_DIM * 2);
  float* bcq              = (float*)alloc(D_DIM * 4);
  float* bck              = (float*)alloc(D_DIM * 4);
  float* bcv              = (float*)alloc(D_DIM * 4);
  int* topk               = (int*)alloc((size_t)B_ROWS * K_TOP * 4);

  float* out_ctx  = (float*)d_out;
  float* out_attn = out_ctx + (size_t)B_ROWS * D_DIM;
  (void)out_ctx;

  // Phase A: converts + transposed weight converts + fused biases
  PrepArgs pa;
  pa.cs[0] = query; pa.cd[0] = q_bf;
  pa.cs[1] = bank;  pa.cd[1] = bank_bf;
  pa.cs[2] = Wq;    pa.cd[2] = wq_bf;
  pa.cs[3] = Wk;    pa.cd[3] = wk_bf;
  pa.cs[4] = Wv;    pa.cd[4] = wv_bf;
  pa.cs[5] = Wo;    pa.cd[5] = wo_bf;
  pa.ts[0] = Wq_proj; pa.td[0] = wqpT_bf;
  pa.ts[1] = Wp_proj; pa.td[1] = wppT_bf;
  pa.bW[0] = Wq; pa.bp[0] = bq_proj; pa.bb[0] = bq; pa.bo[0] = bcq;
  pa.bW[1] = Wk; pa.bp[1] = bp_proj; pa.bb[1] = bk; pa.bo[1] = bck;
  pa.bW[2] = Wv; pa.bp[2] = bp_proj; pa.bb[2] = bv; pa.bo[2] = bcv;
  prep_kernel<<<PREP_BLOCKS, 256, 0, stream>>>(pa);

  // Phase B: weight-fusion GEMMs (MFMA) || top-k (VALU)
  MidArgs ma;
  ma.fA[0] = wq_bf; ma.fW[0] = wqpT_bf; ma.fC[0] = wcq_bf;
  ma.fA[1] = wk_bf; ma.fW[1] = wppT_bf; ma.fC[1] = wck_bf;
  ma.fA[2] = wv_bf; ma.fW[2] = wppT_bf; ma.fC[2] = wcv_bf;
  ma.logits = logits; ma.topk = topk;
  mid_kernel<<<MID_BLOCKS, 256, 0, stream>>>(ma);

  // Phase C: q2 + kb + vb GEMMs in one launch
  Gemm3Args ga;
  ga.A[0] = q_bf;    ga.W[0] = wcq_bf; ga.bias[0] = bcq; ga.C[0] = q2_bf;
  ga.A[1] = bank_bf; ga.W[1] = wck_bf; ga.bias[1] = bck; ga.C[1] = kb_bf;
  ga.A[2] = bank_bf; ga.W[2] = wcv_bf; ga.bias[2] = bcv; ga.C[2] = vb_bf;
  gemm3_kernel<<<GEMM3_BLOCKS, 256, 0, stream>>>(ga);

  // Phase D: attention (ctx overwrites q_bf, which is free now)
  attn_kernel<<<B_ROWS, 256, 0, stream>>>(q2_bf, kb_bf, vb_bf, topk, q_bf, out_attn);

  // Phase E: context = ctx @ Wo^T + bo (fp32 out)
  dim3 grid2(D_DIM / 128, B_ROWS / 128);
  gemm_bt_kernel<false><<<grid2, 256, 0, stream>>>(q_bf, wo_bf, bo, d_out);
}